// Round 8
// baseline (92.407 us; speedup 1.0000x reference)
//
#include <hip/hip_runtime.h>

// Problem constants (from reference setup_inputs)
#define NN 8
#define CC 4
#define HH 64
#define WW 64
#define KK 5
#define FF 16
#define HO 60
#define WO 60
#define PP (KK * KK * CC) /* 100 */

#define RPB 2                    /* output rows per block (and per wave) */
#define HPB (HO / RPB)           /* 30 ho-pairs per n */
#define RIN (RPB + KK - 1)       /* 6 input rows per channel */

#define REPS 3                   /* DIAGNOSTIC: repeat body so the dispatch
                                    exceeds the 40us harness fills and shows
                                    up in rocprof top-5 with full counters.
                                    Outputs identical each rep. */

typedef float v4f __attribute__((ext_vector_type(4)));
typedef float v2f __attribute__((ext_vector_type(2)));

#define PQ_ELEMS (CC * RIN * 64)     /* 1536 */
#define PQ_SIZE (PQ_ELEMS + 4)       /* +4 pad: last-row lanes read lane+kw<=67 */
#define WL_ELEMS (PP * 8)            /* 800: only this block's 8 features */
#define LDS_TOT (PQ_SIZE + WL_ELEMS) /* 2340 v4f = 37.4 KB */

// Round-8 DIAGNOSTIC: rounds 1 and 7 both measure ~31us conv despite 2x
// different LDS traffic -> LDS-read count falsified as bottleneck; true
// bottleneck (spill? latency? issue?) indistinguishable because the conv
// dispatch has never been visible in top-5 counters. This round: (a) REPS=3
// so the dispatch becomes the slowest and surfaces VGPR/VALUBusy/Occupancy/
// WRITE_SIZE; (b) lowest-register-pressure inner loop (no qprev cache --
// proven free; kh a real loop; live ~= 16 accs(32) + 6 loads(24) + addr ~ 70)
// to give the spill hypothesis a clean read.
__global__ __launch_bounds__(512) void smorph_fused(
        const float* __restrict__ x, const float* __restrict__ k1,
        const float* __restrict__ k2, const float* __restrict__ bias,
        float* __restrict__ out) {
    __shared__ v4f lds[LDS_TOT];
    v4f* pq = lds;            // [c][rin][64] pixel quads {e^x, x e^x, e^-x, -x e^-x}
    v4f* wl = lds + PQ_SIZE;  // [p][side][f2l] weight quads {e^ka, e^kb, ka e^ka, kb e^kb}

    int b = blockIdx.x;       // 0..479 = (n, ho-pair, f-half)
    int n = b / (HPB * 2);
    int rem = b - n * (HPB * 2);
    int hp = rem >> 1;
    int fgh = rem & 1;        // feature half: features 8*fgh .. 8*fgh+7
    int ho0 = hp * RPB;
    int t = threadIdx.x;

    int lane = t & 63;  // w position (60 used)
    int wid = t >> 6;   // 0..7
    int cw = wid & 3;   // channel owned by this wave
    int fgl = wid >> 2; // local feature group: local f-pairs 2fgl, 2fgl+1

#pragma unroll 1
    for (int rep = 0; rep < REPS; ++rep) {
        // Stage this f-half's weight exp-quads (800 elems; k1/k2 L2-resident).
        for (int i = t; i < WL_ELEMS; i += 512) {
            int p = i >> 3, r2 = i & 7, side = r2 >> 2, f2l = r2 & 3;
            int f2 = fgh * 4 + f2l; // global feature pair
            const float* kp = side ? k2 : k1;
            float ka = kp[p * FF + 2 * f2];
            float kb = kp[p * FF + 2 * f2 + 1];
            float ea = __expf(ka), eb = __expf(kb);
            wl[i] = (v4f){ea, eb, ka * ea, kb * eb};
        }
        // Stage pixel exp-quads: rows ho0..ho0+5 (ho0<=58 -> row<=63), all c.
        for (int i = t; i < PQ_ELEMS; i += 512) {
            int w = i & 63;
            int cr = i >> 6; // c*RIN + r
            int c = cr / RIN, r = cr - c * RIN;
            float v = x[((n * CC + c) * HH + (ho0 + r)) * WW + w];
            float e1 = __expf(v), e2 = __expf(-v);
            pq[i] = (v4f){e1, v * e1, e2, -v * e2};
        }
        __syncthreads();

        v2f d1[RPB][2], n1[RPB][2], d2[RPB][2], n2[RPB][2];
#pragma unroll
        for (int r = 0; r < RPB; ++r)
#pragma unroll
            for (int jp = 0; jp < 2; ++jp) {
                d1[r][jp] = 0.f; n1[r][jp] = 0.f;
                d2[r][jp] = 0.f; n2[r][jp] = 0.f;
            }

        const v4f* pbase = pq + (cw * RIN) * 64 + lane;
        const v4f* wbase = wl + cw * 8 + fgl * 2;

#pragma unroll 1
        for (int kh = 0; kh < KK; ++kh) {
            const v4f* prow = pbase + kh * 64;
            const v4f* wrow = wbase + (kh * KK) * CC * 8;
#pragma unroll
            for (int kw = 0; kw < KK; ++kw) {
                v4f q  = prow[kw];      // input row kh   (out row 0)
                v4f qn = prow[64 + kw]; // input row kh+1 (out row 1)
                // p = (kh*KK + kw)*CC + cw (reference patch order: kh,kw,c)
                const v4f* wp = wrow + kw * CC * 8;
                v4f w1a = wp[0], w1b = wp[1]; // side 1 (k1), local f-pairs
                v4f w2a = wp[4], w2b = wp[5]; // side 2 (k2)
                d1[0][0] += q.xx * w1a.xy;
                n1[0][0] += q.yy * w1a.xy + q.xx * w1a.zw;
                d1[0][1] += q.xx * w1b.xy;
                n1[0][1] += q.yy * w1b.xy + q.xx * w1b.zw;
                d2[0][0] += q.zz * w2a.xy;
                n2[0][0] += q.ww * w2a.xy + q.zz * w2a.zw;
                d2[0][1] += q.zz * w2b.xy;
                n2[0][1] += q.ww * w2b.xy + q.zz * w2b.zw;
                d1[1][0] += qn.xx * w1a.xy;
                n1[1][0] += qn.yy * w1a.xy + qn.xx * w1a.zw;
                d1[1][1] += qn.xx * w1b.xy;
                n1[1][1] += qn.yy * w1b.xy + qn.xx * w1b.zw;
                d2[1][0] += qn.zz * w2a.xy;
                n2[1][0] += qn.ww * w2a.xy + qn.zz * w2a.zw;
                d2[1][1] += qn.zz * w2b.xy;
                n2[1][1] += qn.ww * w2b.xy + qn.zz * w2b.zw;
            }
        }

        // 4-way c-reduction per row via LDS overlay (pq dead; needs 2048 v4f).
        // red[(cw-1)][fgl][acc 0..3][lane], acc packs {v[jp=0].xy, v[jp=1].xy}.
        v4f* red = lds;
        __syncthreads();
#pragma unroll
        for (int r = 0; r < RPB; ++r) {
            if (r) __syncthreads(); // row-0 reads done before row-1 overwrites
            if (cw) {
                v4f* rr = red + (((cw - 1) * 2 + fgl) * 4) * 64 + lane;
                rr[0 * 64] = (v4f){d1[r][0].x, d1[r][0].y, d1[r][1].x, d1[r][1].y};
                rr[1 * 64] = (v4f){n1[r][0].x, n1[r][0].y, n1[r][1].x, n1[r][1].y};
                rr[2 * 64] = (v4f){d2[r][0].x, d2[r][0].y, d2[r][1].x, d2[r][1].y};
                rr[3 * 64] = (v4f){n2[r][0].x, n2[r][0].y, n2[r][1].x, n2[r][1].y};
            }
            __syncthreads();
            if (!cw) {
#pragma unroll
                for (int rcw = 0; rcw < 3; ++rcw) {
                    const v4f* rr = red + ((rcw * 2 + fgl) * 4) * 64 + lane;
                    v4f t0 = rr[0 * 64], t1 = rr[1 * 64];
                    v4f t2 = rr[2 * 64], t3 = rr[3 * 64];
                    d1[r][0] += t0.xy; d1[r][1] += t0.zw;
                    n1[r][0] += t1.xy; n1[r][1] += t1.zw;
                    d2[r][0] += t2.xy; d2[r][1] += t2.zw;
                    n2[r][0] += t3.xy; n2[r][1] += t3.zw;
                }
                if (lane < WO) {
                    int ho = ho0 + r;
#pragma unroll
                    for (int jp = 0; jp < 2; ++jp) {
                        v2f o = n1[r][jp] / d1[r][jp] + n2[r][jp] / d2[r][jp];
                        int f0 = fgh * 8 + fgl * 4 + 2 * jp;
                        out[((size_t)(n * FF + f0) * HO + ho) * WO + lane] =
                            o.x + bias[f0];
                        out[((size_t)(n * FF + f0 + 1) * HO + ho) * WO + lane] =
                            o.y + bias[f0 + 1];
                    }
                }
            }
        }
        __syncthreads(); // next rep's staging must not race this rep's reads
    }
}

extern "C" void kernel_launch(void* const* d_in, const int* in_sizes, int n_in,
                              void* d_out, int out_size, void* d_ws, size_t ws_size,
                              hipStream_t stream) {
    const float* x    = (const float*)d_in[0];
    const float* k1   = (const float*)d_in[1];
    const float* k2   = (const float*)d_in[2];
    const float* bias = (const float*)d_in[3];
    float* out = (float*)d_out;

    // 480 blocks = 8 n x 30 ho-pairs x 2 f-halves; 512 threads = 8 waves
    // (4 channels x 2 local f-groups), each wave: 2 rows x 4 features x 1 c.
    smorph_fused<<<NN * HPB * 2, 512, 0, stream>>>(x, k1, k2, bias, out);
}

// Round 9
// 70.649 us; speedup vs baseline: 1.3080x; 1.3080x over previous
//
#include <hip/hip_runtime.h>

// Problem constants (from reference setup_inputs)
#define NN 8
#define CC 4
#define HH 64
#define WW 64
#define KK 5
#define FF 16
#define HO 60
#define WO 60
#define PP (KK * KK * CC) /* 100 */

typedef float v4f __attribute__((ext_vector_type(4)));
typedef float v2f __attribute__((ext_vector_type(2)));

#define PQ_ELEMS (CC * KK * 64)      /* 1280: 5 input rows x 4 c x 64 w */
#define PQ_SIZE (PQ_ELEMS + 4)       /* +4 pad: last-row lanes read lane+kw<=67 */
#define WL_ELEMS (PP * 8)            /* 800: this block's 8 features */
#define LDS_TOT (PQ_SIZE + WL_ELEMS) /* 2084 v4f = 33.3 KB -> 4 blocks/CU */

// Round-9: round-8 diagnostic (REPS=3) surfaced the conv counters for the
// first time: VGPR=56 / WRITE=1.8MB -> NO spill; VALUBusy 45%, Occupancy 27%
// -> latency/occupancy-bound. Cause: 480 blocks / 256 CU = 1.875 blocks/CU
// (224 CUs serialize 2 blocks, 32 run 1; <=16 waves/CU resident). Fix: RPB=1,
// 960 blocks (n x 60 ho x 2 f-half), 33.3 KB LDS -> 4 blocks/CU co-resident
// (avg 3.75, imbalance ~7%), accs halve (VGPR ~48). Round-7's null result
// (LDS-read count doesn't matter here) licenses giving up the 2-row weight
// amortization in exchange for occupancy.
__global__ __launch_bounds__(512) void smorph_fused(
        const float* __restrict__ x, const float* __restrict__ k1,
        const float* __restrict__ k2, const float* __restrict__ bias,
        float* __restrict__ out) {
    __shared__ v4f lds[LDS_TOT];
    v4f* pq = lds;            // [c][kr][64] pixel quads {e^x, x e^x, e^-x, -x e^-x}
    v4f* wl = lds + PQ_SIZE;  // [p][side][f2l] weight quads {e^ka, e^kb, ka e^ka, kb e^kb}

    int b = blockIdx.x;       // 0..959 = (n, ho, f-half)
    int n = b / (HO * 2);
    int rem = b - n * (HO * 2);
    int ho = rem >> 1;
    int fgh = rem & 1;        // feature half: features 8*fgh .. 8*fgh+7
    int t = threadIdx.x;

    // Stage this f-half's weight exp-quads (800 elems; k1/k2 L2-resident).
    for (int i = t; i < WL_ELEMS; i += 512) {
        int p = i >> 3, r2 = i & 7, side = r2 >> 2, f2l = r2 & 3;
        int f2 = fgh * 4 + f2l; // global feature pair
        const float* kp = side ? k2 : k1;
        float ka = kp[p * FF + 2 * f2];
        float kb = kp[p * FF + 2 * f2 + 1];
        float ea = __expf(ka), eb = __expf(kb);
        wl[i] = (v4f){ea, eb, ka * ea, kb * eb};
    }
    // Stage pixel exp-quads: input rows ho..ho+4 (ho<=59 -> row<=63), all c.
    for (int i = t; i < PQ_ELEMS; i += 512) {
        int w = i & 63;
        int cr = i >> 6; // c*KK + r
        int c = cr / KK, r = cr - c * KK;
        float v = x[((n * CC + c) * HH + (ho + r)) * WW + w];
        float e1 = __expf(v), e2 = __expf(-v);
        pq[i] = (v4f){e1, v * e1, e2, -v * e2};
    }
    __syncthreads();

    int lane = t & 63;  // w position (60 used)
    int wid = t >> 6;   // 0..7
    int cw = wid & 3;   // channel owned by this wave
    int fgl = wid >> 2; // local feature group: local f-pairs 2fgl, 2fgl+1

    v2f d1[2], n1[2], d2[2], n2[2];
#pragma unroll
    for (int jp = 0; jp < 2; ++jp) {
        d1[jp] = 0.f; n1[jp] = 0.f; d2[jp] = 0.f; n2[jp] = 0.f;
    }

    const v4f* pbase = pq + (cw * KK) * 64 + lane;
    const v4f* wbase = wl + cw * 8 + fgl * 2;

#pragma unroll 1
    for (int kh = 0; kh < KK; ++kh) {
        const v4f* prow = pbase + kh * 64;
        const v4f* wrow = wbase + (kh * KK) * CC * 8;
#pragma unroll
        for (int kw = 0; kw < KK; ++kw) {
            v4f q = prow[kw]; // ds_read_b128, consecutive lanes
            // p = (kh*KK + kw)*CC + cw (reference patch order: kh,kw,c)
            const v4f* wp = wrow + kw * CC * 8;
            v4f w1a = wp[0], w1b = wp[1]; // side 1 (k1), local f-pairs
            v4f w2a = wp[4], w2b = wp[5]; // side 2 (k2)
            d1[0] += q.xx * w1a.xy;
            n1[0] += q.yy * w1a.xy + q.xx * w1a.zw;
            d1[1] += q.xx * w1b.xy;
            n1[1] += q.yy * w1b.xy + q.xx * w1b.zw;
            d2[0] += q.zz * w2a.xy;
            n2[0] += q.ww * w2a.xy + q.zz * w2a.zw;
            d2[1] += q.zz * w2b.xy;
            n2[1] += q.ww * w2b.xy + q.zz * w2b.zw;
        }
    }

    // 4-way c-reduction via LDS overlay (pq dead; needs 1536 v4f <= 2084).
    // red[(cw-1)][fgl][acc 0..3][lane]; acc packs {v[jp=0].xy, v[jp=1].xy}.
    v4f* red = lds;
    __syncthreads();
    if (cw) {
        v4f* rr = red + (((cw - 1) * 2 + fgl) * 4) * 64 + lane;
        rr[0 * 64] = (v4f){d1[0].x, d1[0].y, d1[1].x, d1[1].y};
        rr[1 * 64] = (v4f){n1[0].x, n1[0].y, n1[1].x, n1[1].y};
        rr[2 * 64] = (v4f){d2[0].x, d2[0].y, d2[1].x, d2[1].y};
        rr[3 * 64] = (v4f){n2[0].x, n2[0].y, n2[1].x, n2[1].y};
    }
    __syncthreads();
    if (!cw && lane < WO) {
#pragma unroll
        for (int rcw = 0; rcw < 3; ++rcw) {
            const v4f* rr = red + ((rcw * 2 + fgl) * 4) * 64 + lane;
            v4f t0 = rr[0 * 64], t1 = rr[1 * 64];
            v4f t2 = rr[2 * 64], t3 = rr[3 * 64];
            d1[0] += t0.xy; d1[1] += t0.zw;
            n1[0] += t1.xy; n1[1] += t1.zw;
            d2[0] += t2.xy; d2[1] += t2.zw;
            n2[0] += t3.xy; n2[1] += t3.zw;
        }
#pragma unroll
        for (int jp = 0; jp < 2; ++jp) {
            v2f o = n1[jp] / d1[jp] + n2[jp] / d2[jp];
            int f0 = fgh * 8 + fgl * 4 + 2 * jp;
            out[((size_t)(n * FF + f0) * HO + ho) * WO + lane] = o.x + bias[f0];
            out[((size_t)(n * FF + f0 + 1) * HO + ho) * WO + lane] =
                o.y + bias[f0 + 1];
        }
    }
}

extern "C" void kernel_launch(void* const* d_in, const int* in_sizes, int n_in,
                              void* d_out, int out_size, void* d_ws, size_t ws_size,
                              hipStream_t stream) {
    const float* x    = (const float*)d_in[0];
    const float* k1   = (const float*)d_in[1];
    const float* k2   = (const float*)d_in[2];
    const float* bias = (const float*)d_in[3];
    float* out = (float*)d_out;

    // 960 blocks = 8 n x 60 ho x 2 f-halves; 512 threads = 8 waves
    // (4 channels x 2 local f-groups), each wave: 1 row x 4 features x 1 c.
    smorph_fused<<<NN * HO * 2, 512, 0, stream>>>(x, k1, k2, bias, out);
}